// Round 5
// baseline (162.002 us; speedup 1.0000x reference)
//
#include <hip/hip_runtime.h>
#include <hip/hip_bf16.h>
#include <stdint.h>

#define Bv 2
#define Nv 1000
#define Ev 2000
#define Hv 128
#define Mv 4000  // Bv*Ev

typedef __attribute__((ext_vector_type(8))) short bf16x8;
typedef __attribute__((ext_vector_type(4))) float f32x4;
typedef unsigned short u16;
typedef unsigned int u32;

static __device__ __forceinline__ u32 pack2bf(float a, float b) {
  union { __hip_bfloat162 h; u32 u; } c;
  c.h = __float22bfloat162_rn(make_float2(a, b));
  return c.u;
}
static __device__ __forceinline__ u16 cvt1bf(float a) {
  return (u16)(pack2bf(a, 0.f) & 0xffffu);
}

// edge_network fp32 [H][H][H] -> bf16, same (h,i,j) layout. 2M elems, 8/thread.
__global__ void k_cvt_en(const float* __restrict__ en, u16* __restrict__ enbf) {
  size_t idx = ((size_t)blockIdx.x * 256u + threadIdx.x) * 8u;
  const f32x4* p = (const f32x4*)(en + idx);
  f32x4 a = p[0], b = p[1];
  uint4 o;
  o.x = pack2bf(a.x, a.y);
  o.y = pack2bf(a.z, a.w);
  o.z = pack2bf(b.x, b.y);
  o.w = pack2bf(b.z, b.w);
  *(uint4*)(enbf + idx) = o;
}

// Transpose+convert: src fp32 [R][C] -> dst bf16 [C][Rpad], zero-filled rows R..Rpad.
__global__ void k_tr_cvt(const float* __restrict__ src, u16* __restrict__ dst,
                         int R, int C, int Rpad) {
  __shared__ float tile[32][33];
  const int z = blockIdx.z;
  src += (size_t)z * R * C;
  dst += (size_t)z * C * Rpad;
  const int r0 = blockIdx.x * 32, c0 = blockIdx.y * 32;
  const int tx = threadIdx.x & 31, ty = threadIdx.x >> 5;
#pragma unroll
  for (int rr = 0; rr < 4; ++rr) {
    int r = r0 + ty + rr * 8;
    int c = c0 + tx;
    float v = (r < R && c < C) ? src[(size_t)r * C + c] : 0.f;
    tile[ty + rr * 8][tx] = v;
  }
  __syncthreads();
#pragma unroll
  for (int rr = 0; rr < 4; ++rr) {
    int oc = c0 + ty + rr * 8;  // dst row = src col
    int orr = r0 + tx;          // dst col = src row
    if (oc < C)
      dst[(size_t)oc * Rpad + orr] = cvt1bf(tile[tx][ty + rr * 8]);
  }
}

// Straight fp32 -> bf16 convert (no transpose). n elems, 8/thread.
__global__ void k_cvt(const float* __restrict__ src, u16* __restrict__ dst) {
  size_t idx = ((size_t)blockIdx.x * 256u + threadIdx.x) * 8u;
  const f32x4* p = (const f32x4*)(src + idx);
  f32x4 a = p[0], b = p[1];
  uint4 o;
  o.x = pack2bf(a.x, a.y);
  o.y = pack2bf(a.z, a.w);
  o.z = pack2bf(b.x, b.y);
  o.w = pack2bf(b.z, b.w);
  *(uint4*)(dst + idx) = o;
}

// Split-K GEMM partial: Cacc[m,i] += sum_{k in chunk} A[m,k]*BT[i,k]
template <int M, int KREAL, int KPAD, bool ROWSUM>
__launch_bounds__(256, 4)
__global__ void k_gemm_split(const float* __restrict__ A, const u16* __restrict__ BT,
                             float* __restrict__ Cacc, float* __restrict__ nrmacc) {
  __shared__ u16 AL[64 * 136];
  __shared__ float rowsum[64];
  const int b = blockIdx.z;
  A    += (size_t)b * M * KREAL;
  BT   += (size_t)b * 128 * KPAD;
  Cacc += (size_t)b * M * 128;
  if (ROWSUM) nrmacc += (size_t)b * M;
  const int t = threadIdx.x;
  const int lane = t & 63;
  const int w = t >> 6;
  const int row16 = lane & 15;
  const int kg = lane >> 4;
  const int mrow0 = blockIdx.x * 64;
  const int kc = blockIdx.y * 128;
  const int mtg = (w >> 1) * 2;
  const int itg = (w & 1) * 4;
  f32x4 acc[2][4];
#pragma unroll
  for (int i = 0; i < 2; ++i)
#pragma unroll
    for (int j = 0; j < 4; ++j) acc[i][j] = (f32x4){0.f, 0.f, 0.f, 0.f};
  if (ROWSUM && t < 64) rowsum[t] = 0.f;
  __syncthreads();
#pragma unroll
  for (int r = 0; r < 4; ++r) {
    const int chunk = t + r * 256;
    const int m = chunk >> 4;
    const int jc = (chunk & 15) * 8;
    const int gm = mrow0 + m;
    const int gk = kc + jc;
    f32x4 x0 = {0.f, 0.f, 0.f, 0.f}, x1 = {0.f, 0.f, 0.f, 0.f};
    if (gm < M && gk + 8 <= KREAL) {
      const f32x4* p = (const f32x4*)(A + (size_t)gm * KREAL + gk);
      x0 = p[0];
      x1 = p[1];
    }
    if (ROWSUM) {
      float s8 = x0.x + x0.y + x0.z + x0.w + x1.x + x1.y + x1.z + x1.w;
      s8 += __shfl_down(s8, 8, 16);
      s8 += __shfl_down(s8, 4, 16);
      s8 += __shfl_down(s8, 2, 16);
      s8 += __shfl_down(s8, 1, 16);
      if ((lane & 15) == 0) rowsum[m] += s8;
    }
    uint4 o;
    o.x = pack2bf(x0.x, x0.y);
    o.y = pack2bf(x0.z, x0.w);
    o.z = pack2bf(x1.x, x1.y);
    o.w = pack2bf(x1.z, x1.w);
    *(uint4*)&AL[m * 136 + jc] = o;
  }
  __syncthreads();
#pragma unroll
  for (int kk = 0; kk < 4; ++kk) {
    bf16x8 a[2], bfr[4];
#pragma unroll
    for (int q = 0; q < 2; ++q)
      a[q] = *(const bf16x8*)&AL[((mtg + q) * 16 + row16) * 136 + kk * 32 + kg * 8];
#pragma unroll
    for (int q = 0; q < 4; ++q)
      bfr[q] = *(const bf16x8*)(BT + (size_t)((itg + q) * 16 + row16) * KPAD + kc + kk * 32 + kg * 8);
#pragma unroll
    for (int mi = 0; mi < 2; ++mi)
#pragma unroll
      for (int ii = 0; ii < 4; ++ii)
        acc[mi][ii] = __builtin_amdgcn_mfma_f32_16x16x32_bf16(a[mi], bfr[ii], acc[mi][ii], 0, 0, 0);
  }
  if (ROWSUM && t < 64 && mrow0 + t < M) atomicAdd(&nrmacc[mrow0 + t], rowsum[t]);
#pragma unroll
  for (int mi = 0; mi < 2; ++mi) {
#pragma unroll
    for (int r = 0; r < 4; ++r) {
      const int lrow = (mtg + mi) * 16 + kg * 4 + r;
      const int gm = mrow0 + lrow;
      if (gm < M) {
#pragma unroll
        for (int ii = 0; ii < 4; ++ii)
          atomicAdd(&Cacc[(size_t)gm * 128 + (itg + ii) * 16 + row16], acc[mi][ii][r]);
      }
    }
  }
}

// out = (aggacc + ns) / (norm + 1)
__global__ void k_epi(const float* __restrict__ acc, const float* __restrict__ ns,
                      const float* __restrict__ nrm, float* __restrict__ out) {
  const int idx = (blockIdx.x * 256 + threadIdx.x) * 4;
  f32x4 a = *(const f32x4*)(acc + idx);
  f32x4 s = *(const f32x4*)(ns + idx);
  const int row = idx >> 7;
  float inv = 1.f / (nrm[row] + 1.0f);
  *(f32x4*)(out + idx) = (a + s) * inv;
}

// v3 (swapped operands): neweI[b][i][m] += sum_{h in grp} ev[m,h] * (EN[h] @ emb[m]^T)[i,m]
// A = EN[h] ([i][j], k-contig as-is), B = emb ([m][j], already B^T!). B-frags loaded
// ONCE into regs; barrier-free h-loop; ev-scale folded on fp32 MFMA output.
// grid (32 m-tiles of 64, 4 h-groups of 32, 2 batches), block 256 = 4 waves.
__launch_bounds__(256, 2)
__global__ void k_edge_mix(const float* __restrict__ ev, const float* __restrict__ emb,
                           const u16* __restrict__ enbf, float* __restrict__ neweI) {
  __shared__ float EVL[64 * 36];  // ev slice [64 m][32 h], row stride 36 (16B-aligned, 2-way banks)
  const int t = threadIdx.x;
  const int lane = t & 63;
  const int w = t >> 6;
  const int row16 = lane & 15;
  const int kg = lane >> 4;
  const int b = blockIdx.z;
  const int mt = blockIdx.x;
  const int h0 = blockIdx.y * 32;
  const int iw = w >> 1;               // i-half: wave covers i in [iw*64, +64)
  const int mw = w & 1;                // m-half: wave covers 32 m
  const int mbase = mt * 64 + mw * 32; // within batch

  // stage EVL once: ev[b][mt*64 .. +64][h0 .. h0+32]
  if (t < 64) {
    const int ml = mt * 64 + t;
    const float* src = ev + ((size_t)b * Ev + ml) * Hv + h0;
    const f32x4 z = {0.f, 0.f, 0.f, 0.f};
#pragma unroll
    for (int q = 0; q < 8; ++q) {
      f32x4 v = (ml < Ev) ? *(const f32x4*)(src + q * 4) : z;
      *(f32x4*)&EVL[t * 36 + q * 4] = v;
    }
  }

  // B-frags once: emb[m = mbase + mf*16 + row16][j = kk*32 + kg*8 .. +8] -> bf16 regs
  bf16x8 bfrag[2][4];
#pragma unroll
  for (int mf = 0; mf < 2; ++mf) {
    const int ml = mbase + mf * 16 + row16;
    const float* src = emb + ((size_t)b * Ev + ml) * Hv;
#pragma unroll
    for (int kk = 0; kk < 4; ++kk) {
      f32x4 x0 = {0.f, 0.f, 0.f, 0.f}, x1 = {0.f, 0.f, 0.f, 0.f};
      if (ml < Ev) {
        const f32x4* p = (const f32x4*)(src + kk * 32 + kg * 8);
        x0 = p[0];
        x1 = p[1];
      }
      union { bf16x8 v; uint4 u; } c;
      c.u.x = pack2bf(x0.x, x0.y);
      c.u.y = pack2bf(x0.z, x0.w);
      c.u.z = pack2bf(x1.x, x1.y);
      c.u.w = pack2bf(x1.z, x1.w);
      bfrag[mf][kk] = c.v;
    }
  }
  __syncthreads();

  const f32x4 zero4 = {0.f, 0.f, 0.f, 0.f};
  f32x4 pers[4][2];
#pragma unroll
  for (int fi = 0; fi < 4; ++fi)
#pragma unroll
    for (int mf = 0; mf < 2; ++mf) pers[fi][mf] = zero4;

  const int irow0 = iw * 64 + row16;
#pragma unroll 1
  for (int hh = 0; hh < 32; ++hh) {
    const u16* __restrict__ bh = enbf + (size_t)(h0 + hh) * 16384;
    // all 16 A-frag loads up front (L1-resident 32KB h-plane)
    bf16x8 a[4][4];
#pragma unroll
    for (int kk = 0; kk < 4; ++kk)
#pragma unroll
      for (int fi = 0; fi < 4; ++fi)
        a[kk][fi] = *(const bf16x8*)(bh + (size_t)(irow0 + fi * 16) * 128 + kk * 32 + kg * 8);
    f32x4 q[4][2];
#pragma unroll
    for (int fi = 0; fi < 4; ++fi)
#pragma unroll
      for (int mf = 0; mf < 2; ++mf)
        q[fi][mf] = __builtin_amdgcn_mfma_f32_16x16x32_bf16(a[0][fi], bfrag[mf][0], zero4, 0, 0, 0);
#pragma unroll
    for (int kk = 1; kk < 4; ++kk)
#pragma unroll
      for (int fi = 0; fi < 4; ++fi)
#pragma unroll
        for (int mf = 0; mf < 2; ++mf)
          q[fi][mf] = __builtin_amdgcn_mfma_f32_16x16x32_bf16(a[kk][fi], bfrag[mf][kk], q[fi][mf], 0, 0, 0);
    float evv[2];
#pragma unroll
    for (int mf = 0; mf < 2; ++mf)
      evv[mf] = EVL[(mw * 32 + mf * 16 + row16) * 36 + hh];
#pragma unroll
    for (int fi = 0; fi < 4; ++fi)
#pragma unroll
      for (int mf = 0; mf < 2; ++mf)
        pers[fi][mf] += evv[mf] * q[fi][mf];
  }

  // atomic fold into neweI[b][i][m] (i-major: exactly the agg GEMM's B^T layout)
#pragma unroll
  for (int fi = 0; fi < 4; ++fi) {
#pragma unroll
    for (int mf = 0; mf < 2; ++mf) {
      const int ml = mbase + mf * 16 + row16;
      if (ml < Ev) {
#pragma unroll
        for (int r = 0; r < 4; ++r) {
          const int irow = iw * 64 + fi * 16 + kg * 4 + r;
          atomicAdd(&neweI[((size_t)b * 128 + irow) * 2048 + ml], pers[fi][mf][r]);
        }
      }
    }
  }
}

extern "C" void kernel_launch(void* const* d_in, const int* in_sizes, int n_in,
                              void* d_out, int out_size, void* d_ws, size_t ws_size,
                              hipStream_t stream) {
  const float* ns  = (const float*)d_in[0];  // node_state  [B][N][H]
  const float* ev  = (const float*)d_in[1];  // edge_vec    [B][E][H]
  const float* n2e = (const float*)d_in[2];  // node2edge   [B][E][N]
  const float* e2n = (const float*)d_in[3];  // edge2node   [B][N][E]
  const float* en  = (const float*)d_in[4];  // edge_network[H][H][H]
  float* out = (float*)d_out;

  char* ws = (char*)d_ws;
  // layout (total 8,347,648 B):
  float* embacc  = (float*)(ws);              // [4000][128] f32, 2,048,000 — dead after edge_mix
  float* normacc = (float*)(ws + 2048000);    // [2][1000] f32 (+pad), 8,192
  float* neweI   = (float*)(ws + 2056192);    // [2][128][2048] f32, 2,097,152 (i-major)
  u16*   nsT     = (u16*)  (ws + 2056192);    // [2][128][1024] bf16, 524,288 — overlays neweI early
  u16*   enbf    = (u16*)  (ws + 4153344);    // [128][128][128] bf16, 4,194,304 — dead after edge_mix
  float* aggacc  = (float*)(ws + 4153344);    // [2][1000][128] f32, 1,024,000 — overlays enbf late
  u16*   neweT   = (u16*)  (ws);              // [2][128][2048] bf16, 1,048,576 — overlays embacc late

  hipMemsetAsync(ws, 0, 2056192, stream);                 // zero embacc + normacc
  k_cvt_en <<<dim3(1024),     dim3(256), 0, stream>>>(en, enbf);
  k_tr_cvt <<<dim3(32, 4, 2), dim3(256), 0, stream>>>(ns, nsT, Nv, Hv, 1024);
  k_gemm_split<2000, 1000, 1024, false><<<dim3(32, 8, 2), dim3(256), 0, stream>>>(n2e, nsT, embacc, nullptr);
  hipMemsetAsync(neweI, 0, 2097152, stream);              // nsT dead now
  k_edge_mix<<<dim3(32, 4, 2), dim3(256), 0, stream>>>(ev, embacc, enbf, neweI);
  hipMemsetAsync(aggacc, 0, 1024000, stream);             // enbf dead now
  k_cvt<<<dim3(256), dim3(256), 0, stream>>>(neweI, neweT);  // embacc dead now
  k_gemm_split<1000, 2000, 2048, true><<<dim3(16, 16, 2), dim3(256), 0, stream>>>(e2n, neweT, aggacc, normacc);
  k_epi<<<dim3(250), dim3(256), 0, stream>>>(aggacc, ns, normacc, out);
}

// Round 6
// 119.600 us; speedup vs baseline: 1.3545x; 1.3545x over previous
//
#include <hip/hip_runtime.h>
#include <hip/hip_bf16.h>
#include <stdint.h>

#define Bv 2
#define Nv 1000
#define Ev 2000
#define Hv 128
#define Mv 4000  // Bv*Ev

typedef __attribute__((ext_vector_type(8))) short bf16x8;
typedef __attribute__((ext_vector_type(4))) float f32x4;
typedef unsigned short u16;
typedef unsigned int u32;

static __device__ __forceinline__ u32 pack2bf(float a, float b) {
  union { __hip_bfloat162 h; u32 u; } c;
  c.h = __float22bfloat162_rn(make_float2(a, b));
  return c.u;
}
static __device__ __forceinline__ u16 cvt1bf(float a) {
  return (u16)(pack2bf(a, 0.f) & 0xffffu);
}

// edge_network fp32 [H][H][H] -> bf16, same (h,i,j) layout. 2M elems, 8/thread.
__global__ void k_cvt_en(const float* __restrict__ en, u16* __restrict__ enbf) {
  size_t idx = ((size_t)blockIdx.x * 256u + threadIdx.x) * 8u;
  const f32x4* p = (const f32x4*)(en + idx);
  f32x4 a = p[0], b = p[1];
  uint4 o;
  o.x = pack2bf(a.x, a.y);
  o.y = pack2bf(a.z, a.w);
  o.z = pack2bf(b.x, b.y);
  o.w = pack2bf(b.z, b.w);
  *(uint4*)(enbf + idx) = o;
}

// Transpose+convert: src fp32 [R][C] -> dst bf16 [C][Rpad], zero-filled rows R..Rpad.
__global__ void k_tr_cvt(const float* __restrict__ src, u16* __restrict__ dst,
                         int R, int C, int Rpad) {
  __shared__ float tile[32][33];
  const int z = blockIdx.z;
  src += (size_t)z * R * C;
  dst += (size_t)z * C * Rpad;
  const int r0 = blockIdx.x * 32, c0 = blockIdx.y * 32;
  const int tx = threadIdx.x & 31, ty = threadIdx.x >> 5;
#pragma unroll
  for (int rr = 0; rr < 4; ++rr) {
    int r = r0 + ty + rr * 8;
    int c = c0 + tx;
    float v = (r < R && c < C) ? src[(size_t)r * C + c] : 0.f;
    tile[ty + rr * 8][tx] = v;
  }
  __syncthreads();
#pragma unroll
  for (int rr = 0; rr < 4; ++rr) {
    int oc = c0 + ty + rr * 8;  // dst row = src col
    int orr = r0 + tx;          // dst col = src row
    if (oc < C)
      dst[(size_t)oc * Rpad + orr] = cvt1bf(tile[tx][ty + rr * 8]);
  }
}

// Straight fp32 -> bf16 convert (no transpose). 8 elems/thread.
__global__ void k_cvt(const float* __restrict__ src, u16* __restrict__ dst) {
  size_t idx = ((size_t)blockIdx.x * 256u + threadIdx.x) * 8u;
  const f32x4* p = (const f32x4*)(src + idx);
  f32x4 a = p[0], b = p[1];
  uint4 o;
  o.x = pack2bf(a.x, a.y);
  o.y = pack2bf(a.z, a.w);
  o.z = pack2bf(b.x, b.y);
  o.w = pack2bf(b.z, b.w);
  *(uint4*)(dst + idx) = o;
}

// Split-K GEMM partial: Cacc[m,i] += sum_{k in chunk} A[m,k]*BT[i,k]
template <int M, int KREAL, int KPAD, bool ROWSUM>
__launch_bounds__(256, 4)
__global__ void k_gemm_split(const float* __restrict__ A, const u16* __restrict__ BT,
                             float* __restrict__ Cacc, float* __restrict__ nrmacc) {
  __shared__ u16 AL[64 * 136];
  __shared__ float rowsum[64];
  const int b = blockIdx.z;
  A    += (size_t)b * M * KREAL;
  BT   += (size_t)b * 128 * KPAD;
  Cacc += (size_t)b * M * 128;
  if (ROWSUM) nrmacc += (size_t)b * M;
  const int t = threadIdx.x;
  const int lane = t & 63;
  const int w = t >> 6;
  const int row16 = lane & 15;
  const int kg = lane >> 4;
  const int mrow0 = blockIdx.x * 64;
  const int kc = blockIdx.y * 128;
  const int mtg = (w >> 1) * 2;
  const int itg = (w & 1) * 4;
  f32x4 acc[2][4];
#pragma unroll
  for (int i = 0; i < 2; ++i)
#pragma unroll
    for (int j = 0; j < 4; ++j) acc[i][j] = (f32x4){0.f, 0.f, 0.f, 0.f};
  if (ROWSUM && t < 64) rowsum[t] = 0.f;
  __syncthreads();
#pragma unroll
  for (int r = 0; r < 4; ++r) {
    const int chunk = t + r * 256;
    const int m = chunk >> 4;
    const int jc = (chunk & 15) * 8;
    const int gm = mrow0 + m;
    const int gk = kc + jc;
    f32x4 x0 = {0.f, 0.f, 0.f, 0.f}, x1 = {0.f, 0.f, 0.f, 0.f};
    if (gm < M && gk + 8 <= KREAL) {
      const f32x4* p = (const f32x4*)(A + (size_t)gm * KREAL + gk);
      x0 = p[0];
      x1 = p[1];
    }
    if (ROWSUM) {
      float s8 = x0.x + x0.y + x0.z + x0.w + x1.x + x1.y + x1.z + x1.w;
      s8 += __shfl_down(s8, 8, 16);
      s8 += __shfl_down(s8, 4, 16);
      s8 += __shfl_down(s8, 2, 16);
      s8 += __shfl_down(s8, 1, 16);
      if ((lane & 15) == 0) rowsum[m] += s8;
    }
    uint4 o;
    o.x = pack2bf(x0.x, x0.y);
    o.y = pack2bf(x0.z, x0.w);
    o.z = pack2bf(x1.x, x1.y);
    o.w = pack2bf(x1.z, x1.w);
    *(uint4*)&AL[m * 136 + jc] = o;
  }
  __syncthreads();
#pragma unroll
  for (int kk = 0; kk < 4; ++kk) {
    bf16x8 a[2], bfr[4];
#pragma unroll
    for (int q = 0; q < 2; ++q)
      a[q] = *(const bf16x8*)&AL[((mtg + q) * 16 + row16) * 136 + kk * 32 + kg * 8];
#pragma unroll
    for (int q = 0; q < 4; ++q)
      bfr[q] = *(const bf16x8*)(BT + (size_t)((itg + q) * 16 + row16) * KPAD + kc + kk * 32 + kg * 8);
#pragma unroll
    for (int mi = 0; mi < 2; ++mi)
#pragma unroll
      for (int ii = 0; ii < 4; ++ii)
        acc[mi][ii] = __builtin_amdgcn_mfma_f32_16x16x32_bf16(a[mi], bfr[ii], acc[mi][ii], 0, 0, 0);
  }
  if (ROWSUM && t < 64 && mrow0 + t < M) atomicAdd(&nrmacc[mrow0 + t], rowsum[t]);
#pragma unroll
  for (int mi = 0; mi < 2; ++mi) {
#pragma unroll
    for (int r = 0; r < 4; ++r) {
      const int lrow = (mtg + mi) * 16 + kg * 4 + r;
      const int gm = mrow0 + lrow;
      if (gm < M) {
#pragma unroll
        for (int ii = 0; ii < 4; ++ii)
          atomicAdd(&Cacc[(size_t)gm * 128 + (itg + ii) * 16 + row16], acc[mi][ii][r]);
      }
    }
  }
}

// out = (aggacc + ns) / (norm + 1)
__global__ void k_epi(const float* __restrict__ acc, const float* __restrict__ ns,
                      const float* __restrict__ nrm, float* __restrict__ out) {
  const int idx = (blockIdx.x * 256 + threadIdx.x) * 4;
  f32x4 a = *(const f32x4*)(acc + idx);
  f32x4 s = *(const f32x4*)(ns + idx);
  const int row = idx >> 7;
  float inv = 1.f / (nrm[row] + 1.0f);
  *(f32x4*)(out + idx) = (a + s) * inv;
}

// v4 (swapped operands + reg double-buffered A-pipeline):
// neweI[b][i][m] += sum_{h in grp} ev[m,h] * (EN[h] @ emb^T)[i,m]
// Block: 64 m (B-frags in regs, all waves) x 128 i (wave w owns i in [w*32,+32)).
// 16 h per block; per-h A-frags (EN rows) double-buffered in registers so
// next-h loads overlap current-h MFMAs. Grid (32 mt, 8 hg, 2 b) = 512 blocks.
__launch_bounds__(256, 2)
__global__ void k_edge_mix(const float* __restrict__ ev, const float* __restrict__ emb,
                           const u16* __restrict__ enbf, float* __restrict__ neweI) {
  __shared__ float EVL[64 * 20];  // ev slice [64 m][16 h], stride 20 (16B-aligned, conflict-free)
  const int t = threadIdx.x;
  const int lane = t & 63;
  const int w = t >> 6;
  const int row16 = lane & 15;
  const int kg = lane >> 4;
  const int b = blockIdx.z;
  const int mt = blockIdx.x;
  const int h0 = blockIdx.y * 16;
  const int mbase = mt * 64;

  // stage ev slice once
  if (t < 64) {
    const int ml = mbase + t;
    const float* src = ev + ((size_t)b * Ev + ml) * Hv + h0;
    const f32x4 z = {0.f, 0.f, 0.f, 0.f};
#pragma unroll
    for (int q = 0; q < 4; ++q) {
      f32x4 v = (ml < Ev) ? *(const f32x4*)(src + q * 4) : z;
      *(f32x4*)&EVL[t * 20 + q * 4] = v;
    }
  }

  // B-frags once: emb[mbase + mf*16 + row16][kk*32 + kg*8 ..+8] -> bf16 regs (64 m)
  bf16x8 bfrag[4][4];
#pragma unroll
  for (int mf = 0; mf < 4; ++mf) {
    const int ml = mbase + mf * 16 + row16;
    const float* src = emb + ((size_t)b * Ev + ml) * Hv;
#pragma unroll
    for (int kk = 0; kk < 4; ++kk) {
      f32x4 x0 = {0.f, 0.f, 0.f, 0.f}, x1 = {0.f, 0.f, 0.f, 0.f};
      if (ml < Ev) {
        const f32x4* p = (const f32x4*)(src + kk * 32 + kg * 8);
        x0 = p[0];
        x1 = p[1];
      }
      union { bf16x8 v; uint4 u; } c;
      c.u.x = pack2bf(x0.x, x0.y);
      c.u.y = pack2bf(x0.z, x0.w);
      c.u.z = pack2bf(x1.x, x1.y);
      c.u.w = pack2bf(x1.z, x1.w);
      bfrag[mf][kk] = c.v;
    }
  }
  __syncthreads();

  const f32x4 zero4 = {0.f, 0.f, 0.f, 0.f};
  f32x4 pers[2][4];
#pragma unroll
  for (int fi = 0; fi < 2; ++fi)
#pragma unroll
    for (int mf = 0; mf < 4; ++mf) pers[fi][mf] = zero4;

  const int irow0 = w * 32 + row16;  // wave's i base row (+fi*16)
  const int kcol = kg * 8;

  // A-frag loader: EN[h] rows (i), 8 x 16B per wave slot
  auto LDA = [&](int hh, bf16x8 a[2][4]) {
    const u16* __restrict__ bh = enbf + (size_t)(h0 + hh) * 16384;
#pragma unroll
    for (int fi = 0; fi < 2; ++fi)
#pragma unroll
      for (int kk = 0; kk < 4; ++kk)
        a[fi][kk] = *(const bf16x8*)(bh + (size_t)(irow0 + fi * 16) * 128 + kk * 32 + kcol);
  };
  // per-h compute: 32 MFMA into fresh q, then ev-scaled fold into pers
  auto STEP = [&](int hh, bf16x8 a[2][4]) {
    f32x4 q[2][4];
#pragma unroll
    for (int fi = 0; fi < 2; ++fi)
#pragma unroll
      for (int mf = 0; mf < 4; ++mf)
        q[fi][mf] = __builtin_amdgcn_mfma_f32_16x16x32_bf16(a[fi][0], bfrag[mf][0], zero4, 0, 0, 0);
#pragma unroll
    for (int kk = 1; kk < 4; ++kk)
#pragma unroll
      for (int fi = 0; fi < 2; ++fi)
#pragma unroll
        for (int mf = 0; mf < 4; ++mf)
          q[fi][mf] = __builtin_amdgcn_mfma_f32_16x16x32_bf16(a[fi][kk], bfrag[mf][kk], q[fi][mf], 0, 0, 0);
    float evv[4];
#pragma unroll
    for (int mf = 0; mf < 4; ++mf)
      evv[mf] = EVL[(mf * 16 + row16) * 20 + hh];
#pragma unroll
    for (int fi = 0; fi < 2; ++fi)
#pragma unroll
      for (int mf = 0; mf < 4; ++mf)
        pers[fi][mf] += evv[mf] * q[fi][mf];
  };

  bf16x8 aA[2][4], aB[2][4];
  LDA(0, aA);
#pragma unroll 1
  for (int hh = 0; hh < 16; hh += 2) {
    LDA(hh + 1, aB);   // issue next loads before consuming aA
    STEP(hh, aA);
    if (hh + 2 < 16) LDA(hh + 2, aA);
    STEP(hh + 1, aB);
  }

  // atomic fold into neweI[b][i][m] (i-major = agg GEMM's B^T layout); 16 lanes -> 16 consecutive m
#pragma unroll
  for (int fi = 0; fi < 2; ++fi) {
#pragma unroll
    for (int mf = 0; mf < 4; ++mf) {
      const int ml = mbase + mf * 16 + row16;
      if (ml < Ev) {
#pragma unroll
        for (int r = 0; r < 4; ++r) {
          const int irow = w * 32 + fi * 16 + kg * 4 + r;
          atomicAdd(&neweI[((size_t)b * 128 + irow) * 2048 + ml], pers[fi][mf][r]);
        }
      }
    }
  }
}

extern "C" void kernel_launch(void* const* d_in, const int* in_sizes, int n_in,
                              void* d_out, int out_size, void* d_ws, size_t ws_size,
                              hipStream_t stream) {
  const float* ns  = (const float*)d_in[0];  // node_state  [B][N][H]
  const float* ev  = (const float*)d_in[1];  // edge_vec    [B][E][H]
  const float* n2e = (const float*)d_in[2];  // node2edge   [B][E][N]
  const float* e2n = (const float*)d_in[3];  // edge2node   [B][N][E]
  const float* en  = (const float*)d_in[4];  // edge_network[H][H][H]
  float* out = (float*)d_out;

  char* ws = (char*)d_ws;
  float* embacc  = (float*)(ws);              // [4000][128] f32, 2,048,000 — dead after edge_mix
  float* normacc = (float*)(ws + 2048000);    // [2][1000] f32 (+pad), 8,192
  float* neweI   = (float*)(ws + 2056192);    // [2][128][2048] f32, 2,097,152 (i-major)
  u16*   nsT     = (u16*)  (ws + 2056192);    // [2][128][1024] bf16, 524,288 — overlays neweI early
  u16*   enbf    = (u16*)  (ws + 4153344);    // [128][128][128] bf16, 4,194,304 — dead after edge_mix
  float* aggacc  = (float*)(ws + 4153344);    // [2][1000][128] f32, 1,024,000 — overlays enbf late
  u16*   neweT   = (u16*)  (ws);              // [2][128][2048] bf16, 1,048,576 — overlays embacc late

  hipMemsetAsync(ws, 0, 2056192, stream);                 // zero embacc + normacc
  k_cvt_en <<<dim3(1024),     dim3(256), 0, stream>>>(en, enbf);
  k_tr_cvt <<<dim3(32, 4, 2), dim3(256), 0, stream>>>(ns, nsT, Nv, Hv, 1024);
  k_gemm_split<2000, 1000, 1024, false><<<dim3(32, 8, 2), dim3(256), 0, stream>>>(n2e, nsT, embacc, nullptr);
  hipMemsetAsync(neweI, 0, 2097152, stream);              // nsT dead now
  k_edge_mix<<<dim3(32, 8, 2), dim3(256), 0, stream>>>(ev, embacc, enbf, neweI);
  hipMemsetAsync(aggacc, 0, 1024000, stream);             // enbf dead now
  k_cvt<<<dim3(256), dim3(256), 0, stream>>>(neweI, neweT);  // embacc dead now
  k_gemm_split<1000, 2000, 2048, true><<<dim3(16, 16, 2), dim3(256), 0, stream>>>(e2n, neweT, aggacc, normacc);
  k_epi<<<dim3(250), dim3(256), 0, stream>>>(aggacc, ns, normacc, out);
}